// Round 11
// baseline (5729.731 us; speedup 1.0000x reference)
//
#include <hip/hip_runtime.h>
#include <hip/hip_bf16.h>
#include <math.h>

#define NBATCH 64
#define TSEQ   1000
#define DIN    257
#define HID    128
#define GATES  512   // 4*HID
#define CH     20    // pipeline chunk (timesteps); 50 chunks of 20 = 1000
#define NCHUNK 50
#define PUBSTEP 80   // publish (fence) cadence: every 4 chunks
#define NPUB    13   // 12 at t=79..959, +1 final at t=999
#define KP1    320   // padded K for the pre1 GEMM (257 -> 320 = 5*64)

typedef _Float16 h2    __attribute__((ext_vector_type(2)));
typedef _Float16 h4    __attribute__((ext_vector_type(4)));
typedef _Float16 half8 __attribute__((ext_vector_type(8)));
typedef float    f32x4 __attribute__((ext_vector_type(4)));

__device__ __forceinline__ float fast_sigmoid(float x) {
    return __builtin_amdgcn_rcpf(1.f + __expf(-x));
}
// branchless tanh: tanh(x) = 1 - 2/(exp(2x)+1), exact identity, valid all x
__device__ __forceinline__ float fast_tanh(float x) {
    const float e = __expf(2.f * x);
    return 1.f - 2.f * __builtin_amdgcn_rcpf(e + 1.f);
}
__device__ __forceinline__ half8 cvt8(const float* p) {
    const float4 a = *(const float4*)p;
    const float4 b = *(const float4*)(p + 4);
    half8 t;
    t[0] = (_Float16)a.x; t[1] = (_Float16)a.y;
    t[2] = (_Float16)a.z; t[3] = (_Float16)a.w;
    t[4] = (_Float16)b.x; t[5] = (_Float16)b.y;
    t[6] = (_Float16)b.z; t[7] = (_Float16)b.w;
    return t;
}

// ---------------------------------------------------------------------------
// cvt_rows: f32 [nrows][sk] -> f16 [nrows][dk], zero-padding cols sk..dk-1.
// ---------------------------------------------------------------------------
__global__ __launch_bounds__(256) void cvt_rows(
    const float* __restrict__ src, _Float16* __restrict__ dst,
    int nrows, int sk, int dk)
{
    const int lane   = threadIdx.x & 63;
    const int wid    = (blockIdx.x * 256 + threadIdx.x) >> 6;
    const int nw     = (gridDim.x * 256) >> 6;
    for (int row = wid; row < nrows; row += nw) {
        for (int c0 = 0; c0 < dk; c0 += 256) {
            const int c = c0 + lane * 4;
            if (c >= dk) continue;
            if (c + 4 <= sk) {
                const float4 u = *(const float4*)(src + (size_t)row * sk + c);
                h4 t; t[0] = (_Float16)u.x; t[1] = (_Float16)u.y;
                      t[2] = (_Float16)u.z; t[3] = (_Float16)u.w;
                *(h4*)(dst + (size_t)row * dk + c) = t;
            } else {
#pragma unroll
                for (int jj = 0; jj < 4; ++jj) {
                    const int cc = c + jj;
                    if (cc < dk)
                        dst[(size_t)row * dk + cc] =
                            (cc < sk) ? (_Float16)src[(size_t)row * sk + cc]
                                      : (_Float16)0.f;
                }
            }
        }
    }
}

// ---------------------------------------------------------------------------
// gemm_f16 (proven R9): C = act(A @ W^T + b1 (+b2)); A,W f16, C f32.
// ---------------------------------------------------------------------------
#define BM 128
#define BN 64
#define BK 64
#define LDK 88

template<int ACT>
__global__ __launch_bounds__(256) void gemm_f16(
    const _Float16* __restrict__ A, const _Float16* __restrict__ W,
    const float* __restrict__ b1, const float* __restrict__ b2,
    float* __restrict__ C, int M, int Ka, int Ncols)
{
    __shared__ _Float16 As[BM][LDK];
    __shared__ _Float16 Ws[BN][LDK];

    const int tid  = threadIdx.x;
    const int wave = tid >> 6;
    const int lane = tid & 63;
    const int r    = lane & 15;
    const int q    = lane >> 4;
    const int m0   = blockIdx.y * BM;
    const int n0   = blockIdx.x * BN;
    const int wm   = (wave >> 1) * 64;
    const int wn   = (wave & 1) * 32;

    const int r32 = tid >> 3;        // staging row sub-index 0..31
    const int c8  = (tid & 7) * 8;   // staging k-offset (f16 elems)

    f32x4 acc[4][2];
#pragma unroll
    for (int i = 0; i < 4; ++i)
#pragma unroll
        for (int j = 0; j < 2; ++j) acc[i][j] = f32x4{0.f, 0.f, 0.f, 0.f};

    for (int kc = 0; kc < Ka; kc += BK) {
#pragma unroll
        for (int it = 0; it < 4; ++it) {
            const int row = it * 32 + r32;
            *(half8*)&As[row][c8] =
                *(const half8*)(A + (size_t)(m0 + row) * Ka + kc + c8);
        }
#pragma unroll
        for (int it = 0; it < 2; ++it) {
            const int row  = it * 32 + r32;
            const int wrow = n0 + row;
            half8 t = {};
            if (wrow < Ncols)
                t = *(const half8*)(W + (size_t)wrow * Ka + kc + c8);
            *(half8*)&Ws[row][c8] = t;
        }
        __syncthreads();

#pragma unroll
        for (int s = 0; s < 2; ++s) {
            const int kb = s * 32 + q * 8;
            half8 af[4], wfr[2];
#pragma unroll
            for (int i = 0; i < 4; ++i)
                af[i] = *(const half8*)&As[wm + i * 16 + r][kb];
#pragma unroll
            for (int j = 0; j < 2; ++j)
                wfr[j] = *(const half8*)&Ws[wn + j * 16 + r][kb];
#pragma unroll
            for (int i = 0; i < 4; ++i)
#pragma unroll
                for (int j = 0; j < 2; ++j)
                    acc[i][j] = __builtin_amdgcn_mfma_f32_16x16x32_f16(
                        af[i], wfr[j], acc[i][j], 0, 0, 0);
        }
        __syncthreads();
    }

#pragma unroll
    for (int i = 0; i < 4; ++i) {
#pragma unroll
        for (int j = 0; j < 2; ++j) {
            const int col = n0 + wn + j * 16 + r;
            if (col < Ncols) {
                const float bias = b1[col] + (b2 ? b2[col] : 0.f);
#pragma unroll
                for (int reg = 0; reg < 4; ++reg) {
                    const int row = m0 + wm + i * 16 + q * 4 + reg;
                    float v = acc[i][j][reg] + bias;
                    if (ACT == 1) v = fast_sigmoid(v);
                    C[(size_t)row * Ncols + col] = v;
                }
            }
        }
    }
}

// ---------------------------------------------------------------------------
// lstm_mega R11: TWO CHAINS PER BLOCK (512 thr, 8 waves; waves 0-3 = chain
// 2i, waves 4-7 = chain 2i+1) -> 2 waves/SIMD of INDEPENDENT work.
// R10 post-mortem: fence-halving + poll-destorm changed nothing -> the ~600
// cyc/step over the 1332 floor is intra-wave latency (ds_read, MFMA dep
// chains, transcendentals, barrier) at 1 wave/SIMD with nothing to fill it.
// R1/R4 showed extra waves from the SAME chain add only duplicated issue;
// waves from a DIFFERENT chain add useful issue that fills the stalls.
// Per-wave code, flag cadence, and the proven R6 fence recipe (syncthreads
// drain -> tid0 threadfence -> relaxed flag store; relaxed spin + single
// acquire) are unchanged. CH 40 -> 20 so 2x pre2ck fits LDS (82.5 KB).
// Publish every 80 steps (= 4 chunks): need = (ck>>2)+1, final v=13.
// Grid: 32 L1-blocks + 32 L2-blocks = 64 blocks, all co-resident.
// ---------------------------------------------------------------------------
__global__ __launch_bounds__(512, 1) void lstm_mega(
    const float* __restrict__ pre1, const float* __restrict__ states_in,
    const float* __restrict__ Whh1, const float* __restrict__ Whh2,
    const float* __restrict__ Wih2, const float* __restrict__ bih2,
    const float* __restrict__ bhh2,
    _Float16* __restrict__ h1g,        // [M][128] f16 handoff (mask region)
    _Float16* __restrict__ h2seq,      // [M][128] f16 (bufB) for K5
    float* __restrict__ states_out, int* __restrict__ flags)
{
    const int bid   = blockIdx.x;
    const int layer = bid >> 5;              // 0: chains L1, 1: chains L2
    const int tid   = threadIdx.x;
    const int ci    = tid >> 8;              // chain-in-block 0/1
    const int th    = tid & 255;             // thread within chain half
    const int n     = 2 * (bid & 31) + ci;   // chain id 0..63
    const int w     = th >> 6;               // wave-in-chain 0..3
    const int lane  = tid & 63;
    const int r     = lane & 15;
    const int q     = lane >> 4;
    const int b     = q & 1;
    const int j     = 32 * w + 16 * b + r;   // this lane's output index
    const int h_row0 = layer ? 128 : 0;

    __shared__ __align__(16) _Float16 hbuf[2][2][HID];        // [ci][cur][j]
    __shared__ __align__(16) float pre2ck[2][CH][GATES + 4];  // [ci][ts][col]

    // ---- recurrence weights: wf[g][b2][s], row = 128g + 32w + 16b2 + r
    const float* Whh = layer ? Whh2 : Whh1;
    half8 wf[4][2][4];
#pragma unroll
    for (int g = 0; g < 4; ++g)
#pragma unroll
        for (int b2 = 0; b2 < 2; ++b2) {
            const float* src = Whh + (size_t)(128 * g + 32 * w + 16 * b2 + r) * HID + q * 8;
#pragma unroll
            for (int s = 0; s < 4; ++s) wf[g][b2][s] = cvt8(src + s * 32);
        }

    // ---- layer-2 extra: Wih2 B-frags (wave w owns pre2 cols 128w..128w+127)
    half8 wih[8][4];
    float bias2v[8];
    if (layer == 1) {
#pragma unroll
        for (int fi = 0; fi < 8; ++fi) {
            const int row = 128 * w + 16 * fi + r;
            const float* src = Wih2 + (size_t)row * HID + q * 8;
#pragma unroll
            for (int s = 0; s < 4; ++s) wih[fi][s] = cvt8(src + s * 32);
            bias2v[fi] = bih2[row] + bhh2[row];
        }
    }

    float c_r = states_in[(size_t)(h_row0 + 64 + n) * HID + j];
    if (th < HID)
        hbuf[ci][0][th] = (_Float16)states_in[(size_t)(h_row0 + n) * HID + th];
    __syncthreads();

    // layer-1: pre1 prefetch registers
    const float* pre_n = pre1 + (size_t)n * TSEQ * GATES;
    float pc0 = 0.f, pc1 = 0.f, pc2 = 0.f, pc3 = 0.f;
    float pn0 = 0.f, pn1 = 0.f, pn2 = 0.f, pn3 = 0.f;
    if (layer == 0) {
        pc0 = pre_n[j];           pc1 = pre_n[j + 128];
        pc2 = pre_n[j + 256];     pc3 = pre_n[j + 384];
        pn0 = pre_n[GATES + j];       pn1 = pre_n[GATES + j + 128];
        pn2 = pre_n[GATES + j + 256]; pn3 = pre_n[GATES + j + 384];
    }

    const f32x4 Z = {0.f, 0.f, 0.f, 0.f};
    int cur = 0, ts = 0, ck = 0;   // step-within-chunk, chunk index

    for (int t = 0; t < TSEQ; ++t) {
        // ==== layer-2 chunk head: wait for h1 chunk ck, compute pre2ck ====
        if (layer == 1 && ts == 0) {
            const int need = (ck >> 2) + 1;   // publishes cover 4 chunks each
            if (th == 0) {                    // one relaxed spinner per chain
                while (__hip_atomic_load(flags + n, __ATOMIC_RELAXED,
                                         __HIP_MEMORY_SCOPE_AGENT) < need)
                    __builtin_amdgcn_s_sleep(2);
            }
            __syncthreads();
            // single acquire (flag is monotone -> observes >= need):
            (void)__hip_atomic_load(flags + n, __ATOMIC_ACQUIRE,
                                    __HIP_MEMORY_SCOPE_AGENT);

            const _Float16* hbase = h1g + ((size_t)n * TSEQ + (size_t)ck * CH) * HID;
            // 20 rows = m-tiles {0..15, 16..19 (r&3 replicated)}
#pragma unroll
            for (int mt = 0; mt < 2; ++mt) {
                const int mrow = (mt == 0) ? r : (16 + (r & 3));
                const _Float16* src = hbase + (size_t)mrow * HID + q * 8;
                half8 ax[4];
#pragma unroll
                for (int s = 0; s < 4; ++s)
                    ax[s] = *(const half8*)(src + s * 32);
                f32x4 gacc[8];
#pragma unroll
                for (int fi = 0; fi < 8; ++fi)
                    gacc[fi] = __builtin_amdgcn_mfma_f32_16x16x32_f16(
                        ax[0], wih[fi][0], Z, 0, 0, 0);
#pragma unroll
                for (int s = 1; s < 4; ++s)
#pragma unroll
                    for (int fi = 0; fi < 8; ++fi)
                        gacc[fi] = __builtin_amdgcn_mfma_f32_16x16x32_f16(
                            ax[s], wih[fi][s], gacc[fi], 0, 0, 0);
                if (mt == 0 || q == 0) {
#pragma unroll
                    for (int fi = 0; fi < 8; ++fi)
#pragma unroll
                        for (int reg = 0; reg < 4; ++reg)
                            pre2ck[ci][mt * 16 + 4 * q + reg][128 * w + 16 * fi + r] =
                                gacc[fi][reg] + bias2v[fi];
                }
            }
            __syncthreads();
        }

        // ==== gate pre-activations ====
        float p0, p1, p2, p3;
        if (layer == 0) {
            p0 = pc0; p1 = pc1; p2 = pc2; p3 = pc3;
            pc0 = pn0; pc1 = pn1; pc2 = pn2; pc3 = pn3;
            if (t + 2 < TSEQ) {
                const float* pp = pre_n + (size_t)(t + 2) * GATES + j;
                pn0 = pp[0]; pn1 = pp[128]; pn2 = pp[256]; pn3 = pp[384];
            }
        } else {
            p0 = pre2ck[ci][ts][j];
            p1 = pre2ck[ci][ts][j + 128];
            p2 = pre2ck[ci][ts][j + 256];
            p3 = pre2ck[ci][ts][j + 384];
        }

        // ==== recurrent matvec (MFMA) ====
        half8 hx[4];
#pragma unroll
        for (int s = 0; s < 4; ++s)
            hx[s] = *(const half8*)&hbuf[ci][cur][s * 32 + q * 8];

        f32x4 acc[4][2];
#pragma unroll
        for (int g = 0; g < 4; ++g)
#pragma unroll
            for (int b2 = 0; b2 < 2; ++b2)
                acc[g][b2] = __builtin_amdgcn_mfma_f32_16x16x32_f16(
                    hx[0], wf[g][b2][0], Z, 0, 0, 0);
#pragma unroll
        for (int s = 1; s < 4; ++s)
#pragma unroll
            for (int g = 0; g < 4; ++g)
#pragma unroll
                for (int b2 = 0; b2 < 2; ++b2)
                    acc[g][b2] = __builtin_amdgcn_mfma_f32_16x16x32_f16(
                        hx[s], wf[g][b2][s], acc[g][b2], 0, 0, 0);

        const float A0 = (b ? acc[0][1][0] : acc[0][0][0]) + p0;
        const float A1 = (b ? acc[1][1][0] : acc[1][0][0]) + p1;
        const float A2 = (b ? acc[2][1][0] : acc[2][0][0]) + p2;
        const float A3 = (b ? acc[3][1][0] : acc[3][0][0]) + p3;

        const float gi = fast_sigmoid(A0);
        const float gf = fast_sigmoid(A1);
        const float gg = fast_tanh(A2);
        const float go = fast_sigmoid(A3);

        const float cn = gf * c_r + gi * gg;
        const float hh = go * fast_tanh(cn);
        c_r = cn;

        // ==== state writes ====
        if (q < 2) {
            hbuf[ci][cur ^ 1][j] = (_Float16)hh;
            if (t == TSEQ - 1)
                states_out[(size_t)(h_row0 + 64 + n) * HID + j] = cn;
        } else {
            if (layer == 0)
                h1g[((size_t)n * TSEQ + t) * HID + j] = (_Float16)hh;
            else
                h2seq[((size_t)n * TSEQ + t) * HID + j] = (_Float16)hh;
            if (t == TSEQ - 1)
                states_out[(size_t)(h_row0 + n) * HID + j] = hh;
        }
        __syncthreads();   // drains vmcnt(0) per wave: stores complete

        // ==== layer-1 publish (every 80 steps + final), proven recipe ====
        if (layer == 0 && tid == 0 &&
            (((t + 1) % PUBSTEP) == 0 || t == TSEQ - 1)) {
            __threadfence();   // agent release (wbl2): h1g chunks visible
            const int v = (t == TSEQ - 1) ? NPUB : (t + 1) / PUBSTEP;
            __hip_atomic_store(flags + n, v,
                               __ATOMIC_RELAXED, __HIP_MEMORY_SCOPE_AGENT);
            __hip_atomic_store(flags + n + 1, v,
                               __ATOMIC_RELAXED, __HIP_MEMORY_SCOPE_AGENT);
        }

        if (++ts == CH) { ts = 0; ++ck; }
        cur ^= 1;
    }
}

// ---------------------------------------------------------------------------
extern "C" void kernel_launch(void* const* d_in, const int* in_sizes, int n_in,
                              void* d_out, int out_size, void* d_ws, size_t ws_size,
                              hipStream_t stream)
{
    const float* x     = (const float*)d_in[0];
    const float* st_in = (const float*)d_in[1];
    const float* Wih1  = (const float*)d_in[2];
    const float* Whh1  = (const float*)d_in[3];
    const float* bih1  = (const float*)d_in[4];
    const float* bhh1  = (const float*)d_in[5];
    const float* Wih2  = (const float*)d_in[6];
    const float* Whh2  = (const float*)d_in[7];
    const float* bih2  = (const float*)d_in[8];
    const float* bhh2  = (const float*)d_in[9];
    const float* Wd    = (const float*)d_in[10];
    const float* bd    = (const float*)d_in[11];

    float* out_mask   = (float*)d_out;
    float* out_states = (float*)d_out + (size_t)NBATCH * TSEQ * DIN;

    const int M = NBATCH * TSEQ;
    float* bufA = (float*)d_ws;               // [M,512] f32 pre1
    float* bufB = bufA + (size_t)M * GATES;   // h2seq f16 + converted weights

    // bufB carve-up: h2seq f16 [M][128] (16.4MB), then Wih1h, then Wdh.
    _Float16* h2seq = (_Float16*)bufB;
    _Float16* wih1h = h2seq + (size_t)M * HID;            // [512][320]
    _Float16* wdh   = wih1h + (size_t)GATES * KP1;        // [257][128]

    // mask-region carve-up (overwritten by K5 strictly afterwards):
    //   xh f16 [M][320] (41MB), h1g f16 [M][128] (16.4MB), flags at tail.
    _Float16* xh  = (_Float16*)out_mask;
    _Float16* h1g = xh + (size_t)M * KP1;
    int* flags = (int*)(out_mask + (size_t)NBATCH * TSEQ * DIN) - 64;
    hipMemsetAsync(flags, 0, 64 * sizeof(int), stream);

    // K0: f32 -> f16 conversions (memory-bound, ~18us total)
    cvt_rows<<<256, 256, 0, stream>>>(x,    xh,    M,     DIN, KP1);
    cvt_rows<<<8,   256, 0, stream>>>(Wih1, wih1h, GATES, DIN, KP1);
    cvt_rows<<<8,   256, 0, stream>>>(Wd,   wdh,   DIN,   HID, HID);

    // K1: pre1 = xh @ Wih1h^T + bih1 + bhh1   (f16 in, M=64000, Ka=320)
    gemm_f16<0><<<dim3(GATES / BN, M / BM), 256, 0, stream>>>(
        xh, wih1h, bih1, bhh1, bufA, M, KP1, GATES);

    // K2: fused pipelined L1 rec -> h1 handoff -> (pre2 on reader) -> L2 rec
    // 64 blocks x 512 thr: 2 chains/block, 2 waves/SIMD of independent work.
    lstm_mega<<<64, 512, 0, stream>>>(
        bufA, st_in, Whh1, Whh2, Wih2, bih2, bhh2, h1g, h2seq, out_states, flags);

    // K5: mask = sigmoid(h2seq @ Wdh^T + bd)   (f16 in, Ka=128, N=257)
    gemm_f16<1><<<dim3((DIN + BN - 1) / BN, M / BM), 256, 0, stream>>>(
        h2seq, wdh, bd, nullptr, out_mask, M, HID, DIN);
}

// Round 12
// 1075.090 us; speedup vs baseline: 5.3295x; 5.3295x over previous
//
#include <hip/hip_runtime.h>
#include <hip/hip_bf16.h>
#include <math.h>

#define NBATCH 64
#define TSEQ   1000
#define DIN    257
#define HID    128
#define GATES  512   // 4*HID
#define CH     40    // pipeline chunk (timesteps); 25 chunks of 40 = 1000
#define NCHUNK 25
#define PUBSTEP 80   // publish (fence) cadence: every 2 chunks
#define NPUB    13   // 12 at t=79..959, +1 final at t=999
#define KP1    320   // padded K for the pre1 GEMM (257 -> 320 = 5*64)

typedef _Float16 h2    __attribute__((ext_vector_type(2)));
typedef _Float16 h4    __attribute__((ext_vector_type(4)));
typedef _Float16 half8 __attribute__((ext_vector_type(8)));
typedef float    f32x4 __attribute__((ext_vector_type(4)));

__device__ __forceinline__ float fast_sigmoid(float x) {
    return __builtin_amdgcn_rcpf(1.f + __expf(-x));
}
// branchless tanh: tanh(x) = 1 - 2/(exp(2x)+1), exact identity, valid all x
__device__ __forceinline__ float fast_tanh(float x) {
    const float e = __expf(2.f * x);
    return 1.f - 2.f * __builtin_amdgcn_rcpf(e + 1.f);
}
__device__ __forceinline__ half8 cvt8(const float* p) {
    const float4 a = *(const float4*)p;
    const float4 b = *(const float4*)(p + 4);
    half8 t;
    t[0] = (_Float16)a.x; t[1] = (_Float16)a.y;
    t[2] = (_Float16)a.z; t[3] = (_Float16)a.w;
    t[4] = (_Float16)b.x; t[5] = (_Float16)b.y;
    t[6] = (_Float16)b.z; t[7] = (_Float16)b.w;
    return t;
}
// agent-scope cache-bypassing 16B read as two 8B relaxed atomic loads
// (reads the device coherence point directly; no buffer_inv emitted)
__device__ __forceinline__ half8 ld_agent16(const _Float16* p) {
    unsigned long long lo = __hip_atomic_load(
        (const unsigned long long*)p, __ATOMIC_RELAXED, __HIP_MEMORY_SCOPE_AGENT);
    unsigned long long hi = __hip_atomic_load(
        (const unsigned long long*)(p + 4), __ATOMIC_RELAXED, __HIP_MEMORY_SCOPE_AGENT);
    const h4 l4 = __builtin_bit_cast(h4, lo);
    const h4 h4_ = __builtin_bit_cast(h4, hi);
    half8 t;
    t[0] = l4[0]; t[1] = l4[1]; t[2] = l4[2]; t[3] = l4[3];
    t[4] = h4_[0]; t[5] = h4_[1]; t[6] = h4_[2]; t[7] = h4_[3];
    return t;
}

// ---------------------------------------------------------------------------
// cvt_rows: f32 [nrows][sk] -> f16 [nrows][dk], zero-padding cols sk..dk-1.
// ---------------------------------------------------------------------------
__global__ __launch_bounds__(256) void cvt_rows(
    const float* __restrict__ src, _Float16* __restrict__ dst,
    int nrows, int sk, int dk)
{
    const int lane   = threadIdx.x & 63;
    const int wid    = (blockIdx.x * 256 + threadIdx.x) >> 6;
    const int nw     = (gridDim.x * 256) >> 6;
    for (int row = wid; row < nrows; row += nw) {
        for (int c0 = 0; c0 < dk; c0 += 256) {
            const int c = c0 + lane * 4;
            if (c >= dk) continue;
            if (c + 4 <= sk) {
                const float4 u = *(const float4*)(src + (size_t)row * sk + c);
                h4 t; t[0] = (_Float16)u.x; t[1] = (_Float16)u.y;
                      t[2] = (_Float16)u.z; t[3] = (_Float16)u.w;
                *(h4*)(dst + (size_t)row * dk + c) = t;
            } else {
#pragma unroll
                for (int jj = 0; jj < 4; ++jj) {
                    const int cc = c + jj;
                    if (cc < dk)
                        dst[(size_t)row * dk + cc] =
                            (cc < sk) ? (_Float16)src[(size_t)row * sk + cc]
                                      : (_Float16)0.f;
                }
            }
        }
    }
}

// ---------------------------------------------------------------------------
// gemm_f16 (proven R9): C = act(A @ W^T + b1 (+b2)); A,W f16, C f32.
// ---------------------------------------------------------------------------
#define BM 128
#define BN 64
#define BK 64
#define LDK 88

template<int ACT>
__global__ __launch_bounds__(256) void gemm_f16(
    const _Float16* __restrict__ A, const _Float16* __restrict__ W,
    const float* __restrict__ b1, const float* __restrict__ b2,
    float* __restrict__ C, int M, int Ka, int Ncols)
{
    __shared__ _Float16 As[BM][LDK];
    __shared__ _Float16 Ws[BN][LDK];

    const int tid  = threadIdx.x;
    const int wave = tid >> 6;
    const int lane = tid & 63;
    const int r    = lane & 15;
    const int q    = lane >> 4;
    const int m0   = blockIdx.y * BM;
    const int n0   = blockIdx.x * BN;
    const int wm   = (wave >> 1) * 64;
    const int wn   = (wave & 1) * 32;

    const int r32 = tid >> 3;        // staging row sub-index 0..31
    const int c8  = (tid & 7) * 8;   // staging k-offset (f16 elems)

    f32x4 acc[4][2];
#pragma unroll
    for (int i = 0; i < 4; ++i)
#pragma unroll
        for (int j = 0; j < 2; ++j) acc[i][j] = f32x4{0.f, 0.f, 0.f, 0.f};

    for (int kc = 0; kc < Ka; kc += BK) {
#pragma unroll
        for (int it = 0; it < 4; ++it) {
            const int row = it * 32 + r32;
            *(half8*)&As[row][c8] =
                *(const half8*)(A + (size_t)(m0 + row) * Ka + kc + c8);
        }
#pragma unroll
        for (int it = 0; it < 2; ++it) {
            const int row  = it * 32 + r32;
            const int wrow = n0 + row;
            half8 t = {};
            if (wrow < Ncols)
                t = *(const half8*)(W + (size_t)wrow * Ka + kc + c8);
            *(half8*)&Ws[row][c8] = t;
        }
        __syncthreads();

#pragma unroll
        for (int s = 0; s < 2; ++s) {
            const int kb = s * 32 + q * 8;
            half8 af[4], wfr[2];
#pragma unroll
            for (int i = 0; i < 4; ++i)
                af[i] = *(const half8*)&As[wm + i * 16 + r][kb];
#pragma unroll
            for (int j = 0; j < 2; ++j)
                wfr[j] = *(const half8*)&Ws[wn + j * 16 + r][kb];
#pragma unroll
            for (int i = 0; i < 4; ++i)
#pragma unroll
                for (int j = 0; j < 2; ++j)
                    acc[i][j] = __builtin_amdgcn_mfma_f32_16x16x32_f16(
                        af[i], wfr[j], acc[i][j], 0, 0, 0);
        }
        __syncthreads();
    }

#pragma unroll
    for (int i = 0; i < 4; ++i) {
#pragma unroll
        for (int j = 0; j < 2; ++j) {
            const int col = n0 + wn + j * 16 + r;
            if (col < Ncols) {
                const float bias = b1[col] + (b2 ? b2[col] : 0.f);
#pragma unroll
                for (int reg = 0; reg < 4; ++reg) {
                    const int row = m0 + wm + i * 16 + q * 4 + reg;
                    float v = acc[i][j][reg] + bias;
                    if (ACT == 1) v = fast_sigmoid(v);
                    C[(size_t)row * Ncols + col] = v;
                }
            }
        }
    }
}

// ---------------------------------------------------------------------------
// lstm_mega R12: R9/R10-verbatim pipeline (256-thr blocks — R11 proved
// 512-thr blocks are VGPR-capped at 128 and spill the weights), with ONE
// change: the L2 chunk-head ACQUIRE is deleted. Theory (R10 falsified the
// fence/poll costs): the one buffer_inv per chunk head per L2 block (~every
// 5 steps per XCD with 16 blocks/XCD) was evicting the co-located L1
// blocks' pre1 stream from L2, exposing IC-latency at each per-step
// vmcnt(0) barrier drain — the +612 cyc/step inflation vs the R2 standalone
// step. Instead, h1g is read with RELAXED AGENT-scope 8B atomic loads
// (cache-bypassing, read the IC coherence point — the same mechanism the
// R10-validated relaxed flag spin relies on). Writer-side release is
// unchanged and proven: vmcnt(0) drain -> __threadfence (wbl2) -> flag.
// ---------------------------------------------------------------------------
__global__ __launch_bounds__(256, 1) void lstm_mega(
    const float* __restrict__ pre1, const float* __restrict__ states_in,
    const float* __restrict__ Whh1, const float* __restrict__ Whh2,
    const float* __restrict__ Wih2, const float* __restrict__ bih2,
    const float* __restrict__ bhh2,
    _Float16* __restrict__ h1g,        // [M][128] f16 handoff (mask region)
    _Float16* __restrict__ h2seq,      // [M][128] f16 (bufB) for K5
    float* __restrict__ states_out, int* __restrict__ flags)
{
    const int layer = blockIdx.x >> 6;
    const int n     = blockIdx.x & 63;
    const int tid   = threadIdx.x;
    const int w     = tid >> 6;
    const int lane  = tid & 63;
    const int r     = lane & 15;
    const int q     = lane >> 4;
    const int b     = q & 1;
    const int j     = 32 * w + 16 * b + r;   // this lane's output index
    const int h_row0 = layer ? 128 : 0;

    __shared__ __align__(16) _Float16 hbuf[2][HID];
    __shared__ __align__(16) float pre2ck[CH][GATES + 4];

    // ---- recurrence weights: wf[g][b2][s], row = 128g + 32w + 16b2 + r
    const float* Whh = layer ? Whh2 : Whh1;
    half8 wf[4][2][4];
#pragma unroll
    for (int g = 0; g < 4; ++g)
#pragma unroll
        for (int b2 = 0; b2 < 2; ++b2) {
            const float* src = Whh + (size_t)(128 * g + 32 * w + 16 * b2 + r) * HID + q * 8;
#pragma unroll
            for (int s = 0; s < 4; ++s) wf[g][b2][s] = cvt8(src + s * 32);
        }

    // ---- layer-2 extra: Wih2 B-frags (wave w owns pre2 cols 128w..128w+127)
    half8 wih[8][4];
    float bias2v[8];
    if (layer == 1) {
#pragma unroll
        for (int fi = 0; fi < 8; ++fi) {
            const int row = 128 * w + 16 * fi + r;
            const float* src = Wih2 + (size_t)row * HID + q * 8;
#pragma unroll
            for (int s = 0; s < 4; ++s) wih[fi][s] = cvt8(src + s * 32);
            bias2v[fi] = bih2[row] + bhh2[row];
        }
    }

    float c_r = states_in[(size_t)(h_row0 + 64 + n) * HID + j];
    if (tid < HID)
        hbuf[0][tid] = (_Float16)states_in[(size_t)(h_row0 + n) * HID + tid];
    __syncthreads();

    // layer-1: pre1 prefetch registers
    const float* pre_n = pre1 + (size_t)n * TSEQ * GATES;
    float pc0 = 0.f, pc1 = 0.f, pc2 = 0.f, pc3 = 0.f;
    float pn0 = 0.f, pn1 = 0.f, pn2 = 0.f, pn3 = 0.f;
    if (layer == 0) {
        pc0 = pre_n[j];           pc1 = pre_n[j + 128];
        pc2 = pre_n[j + 256];     pc3 = pre_n[j + 384];
        pn0 = pre_n[GATES + j];       pn1 = pre_n[GATES + j + 128];
        pn2 = pre_n[GATES + j + 256]; pn3 = pre_n[GATES + j + 384];
    }

    const f32x4 Z = {0.f, 0.f, 0.f, 0.f};
    int cur = 0, ts = 0, ck = 0;   // step-within-chunk, chunk index

    for (int t = 0; t < TSEQ; ++t) {
        // ==== layer-2 chunk head: wait for h1 chunk ck, compute pre2ck ====
        if (layer == 1 && ts == 0) {
            const int need = (ck >> 1) + 1;   // publishes cover 2 chunks each
            if (tid == 0) {                   // relaxed spin (R10-validated)
                while (__hip_atomic_load(flags + n, __ATOMIC_RELAXED,
                                         __HIP_MEMORY_SCOPE_AGENT) < need)
                    __builtin_amdgcn_s_sleep(2);
            }
            __syncthreads();
            // NO acquire here (R12): its buffer_inv poisoned the co-located
            // L1 blocks' L2-cached pre1 stream. h1g is read below with
            // cache-bypassing agent-scope loads instead.

            const _Float16* hbase = h1g + ((size_t)n * TSEQ + (size_t)ck * CH) * HID;
#pragma unroll
            for (int mt = 0; mt < 3; ++mt) {
                const int mrow = (mt < 2) ? (mt * 16 + r) : (32 + (r & 7));
                const _Float16* src = hbase + (size_t)mrow * HID + q * 8;
                half8 ax[4];
#pragma unroll
                for (int s = 0; s < 4; ++s)
                    ax[s] = ld_agent16(src + s * 32);
                f32x4 gacc[8];
#pragma unroll
                for (int fi = 0; fi < 8; ++fi)
                    gacc[fi] = __builtin_amdgcn_mfma_f32_16x16x32_f16(
                        ax[0], wih[fi][0], Z, 0, 0, 0);
#pragma unroll
                for (int s = 1; s < 4; ++s)
#pragma unroll
                    for (int fi = 0; fi < 8; ++fi)
                        gacc[fi] = __builtin_amdgcn_mfma_f32_16x16x32_f16(
                            ax[s], wih[fi][s], gacc[fi], 0, 0, 0);
                if (mt < 2 || q < 2) {
#pragma unroll
                    for (int fi = 0; fi < 8; ++fi)
#pragma unroll
                        for (int reg = 0; reg < 4; ++reg)
                            pre2ck[mt * 16 + 4 * q + reg][128 * w + 16 * fi + r] =
                                gacc[fi][reg] + bias2v[fi];
                }
            }
            __syncthreads();
        }

        // ==== gate pre-activations ====
        float p0, p1, p2, p3;
        if (layer == 0) {
            p0 = pc0; p1 = pc1; p2 = pc2; p3 = pc3;
            pc0 = pn0; pc1 = pn1; pc2 = pn2; pc3 = pn3;
            if (t + 2 < TSEQ) {
                const float* pp = pre_n + (size_t)(t + 2) * GATES + j;
                pn0 = pp[0]; pn1 = pp[128]; pn2 = pp[256]; pn3 = pp[384];
            }
        } else {
            p0 = pre2ck[ts][j];
            p1 = pre2ck[ts][j + 128];
            p2 = pre2ck[ts][j + 256];
            p3 = pre2ck[ts][j + 384];
        }

        // ==== recurrent matvec (MFMA) ====
        half8 hx[4];
#pragma unroll
        for (int s = 0; s < 4; ++s)
            hx[s] = *(const half8*)&hbuf[cur][s * 32 + q * 8];

        f32x4 acc[4][2];
#pragma unroll
        for (int g = 0; g < 4; ++g)
#pragma unroll
            for (int b2 = 0; b2 < 2; ++b2)
                acc[g][b2] = __builtin_amdgcn_mfma_f32_16x16x32_f16(
                    hx[0], wf[g][b2][0], Z, 0, 0, 0);
#pragma unroll
        for (int s = 1; s < 4; ++s)
#pragma unroll
            for (int g = 0; g < 4; ++g)
#pragma unroll
                for (int b2 = 0; b2 < 2; ++b2)
                    acc[g][b2] = __builtin_amdgcn_mfma_f32_16x16x32_f16(
                        hx[s], wf[g][b2][s], acc[g][b2], 0, 0, 0);

        const float A0 = (b ? acc[0][1][0] : acc[0][0][0]) + p0;
        const float A1 = (b ? acc[1][1][0] : acc[1][0][0]) + p1;
        const float A2 = (b ? acc[2][1][0] : acc[2][0][0]) + p2;
        const float A3 = (b ? acc[3][1][0] : acc[3][0][0]) + p3;

        const float gi = fast_sigmoid(A0);
        const float gf = fast_sigmoid(A1);
        const float gg = fast_tanh(A2);
        const float go = fast_sigmoid(A3);

        const float cn = gf * c_r + gi * gg;
        const float hh = go * fast_tanh(cn);
        c_r = cn;

        // ==== state writes ====
        if (q < 2) {
            hbuf[cur ^ 1][j] = (_Float16)hh;
            if (t == TSEQ - 1)
                states_out[(size_t)(h_row0 + 64 + n) * HID + j] = cn;
        } else {
            if (layer == 0)
                h1g[((size_t)n * TSEQ + t) * HID + j] = (_Float16)hh;
            else
                h2seq[((size_t)n * TSEQ + t) * HID + j] = (_Float16)hh;
            if (t == TSEQ - 1)
                states_out[(size_t)(h_row0 + n) * HID + j] = hh;
        }
        __syncthreads();   // drains vmcnt(0) per wave: stores complete

        // ==== layer-1 publish (every 80 steps + final), proven recipe ====
        if (layer == 0 && tid == 0 &&
            (((t + 1) % PUBSTEP) == 0 || t == TSEQ - 1)) {
            __threadfence();   // agent release (wbl2): h1g chunks visible
            const int v = (t == TSEQ - 1) ? NPUB : (t + 1) / PUBSTEP;
            __hip_atomic_store(flags + n, v,
                               __ATOMIC_RELAXED, __HIP_MEMORY_SCOPE_AGENT);
        }

        if (++ts == CH) { ts = 0; ++ck; }
        cur ^= 1;
    }
}

// ---------------------------------------------------------------------------
extern "C" void kernel_launch(void* const* d_in, const int* in_sizes, int n_in,
                              void* d_out, int out_size, void* d_ws, size_t ws_size,
                              hipStream_t stream)
{
    const float* x     = (const float*)d_in[0];
    const float* st_in = (const float*)d_in[1];
    const float* Wih1  = (const float*)d_in[2];
    const float* Whh1  = (const float*)d_in[3];
    const float* bih1  = (const float*)d_in[4];
    const float* bhh1  = (const float*)d_in[5];
    const float* Wih2  = (const float*)d_in[6];
    const float* Whh2  = (const float*)d_in[7];
    const float* bih2  = (const float*)d_in[8];
    const float* bhh2  = (const float*)d_in[9];
    const float* Wd    = (const float*)d_in[10];
    const float* bd    = (const float*)d_in[11];

    float* out_mask   = (float*)d_out;
    float* out_states = (float*)d_out + (size_t)NBATCH * TSEQ * DIN;

    const int M = NBATCH * TSEQ;
    float* bufA = (float*)d_ws;               // [M,512] f32 pre1
    float* bufB = bufA + (size_t)M * GATES;   // h2seq f16 + converted weights

    // bufB carve-up: h2seq f16 [M][128] (16.4MB), then Wih1h, then Wdh.
    _Float16* h2seq = (_Float16*)bufB;
    _Float16* wih1h = h2seq + (size_t)M * HID;            // [512][320]
    _Float16* wdh   = wih1h + (size_t)GATES * KP1;        // [257][128]

    // mask-region carve-up (overwritten by K5 strictly afterwards):
    //   xh f16 [M][320] (41MB), h1g f16 [M][128] (16.4MB), flags at tail.
    _Float16* xh  = (_Float16*)out_mask;
    _Float16* h1g = xh + (size_t)M * KP1;
    int* flags = (int*)(out_mask + (size_t)NBATCH * TSEQ * DIN) - 64;
    hipMemsetAsync(flags, 0, 64 * sizeof(int), stream);

    // K0: f32 -> f16 conversions (memory-bound, ~18us total)
    cvt_rows<<<256, 256, 0, stream>>>(x,    xh,    M,     DIN, KP1);
    cvt_rows<<<8,   256, 0, stream>>>(Wih1, wih1h, GATES, DIN, KP1);
    cvt_rows<<<8,   256, 0, stream>>>(Wd,   wdh,   DIN,   HID, HID);

    // K1: pre1 = xh @ Wih1h^T + bih1 + bhh1   (f16 in, M=64000, Ka=320)
    gemm_f16<0><<<dim3(GATES / BN, M / BM), 256, 0, stream>>>(
        xh, wih1h, bih1, bhh1, bufA, M, KP1, GATES);

    // K2: fused pipelined L1 rec -> h1 handoff -> (pre2 on reader) -> L2 rec
    lstm_mega<<<128, 256, 0, stream>>>(
        bufA, st_in, Whh1, Whh2, Wih2, bih2, bhh2, h1g, h2seq, out_states, flags);

    // K5: mask = sigmoid(h2seq @ Wdh^T + bd)   (f16 in, Ka=128, N=257)
    gemm_f16<1><<<dim3((DIN + BN - 1) / BN, M / BM), 256, 0, stream>>>(
        h2seq, wdh, bd, nullptr, out_mask, M, HID, DIN);
}

// Round 13
// 1047.855 us; speedup vs baseline: 5.4681x; 1.0260x over previous
//
#include <hip/hip_runtime.h>
#include <hip/hip_bf16.h>
#include <math.h>

#define NBATCH 64
#define TSEQ   1000
#define DIN    257
#define HID    128
#define GATES  512   // 4*HID
#define CH     40    // pipeline chunk (timesteps); 25 chunks of 40 = 1000
#define NCHUNK 25
#define KP1    320   // padded K for the pre1 GEMM (257 -> 320 = 5*64)

typedef _Float16 h2    __attribute__((ext_vector_type(2)));
typedef _Float16 h4    __attribute__((ext_vector_type(4)));
typedef _Float16 half8 __attribute__((ext_vector_type(8)));
typedef float    f32x4 __attribute__((ext_vector_type(4)));

__device__ __forceinline__ float fast_sigmoid(float x) {
    return __builtin_amdgcn_rcpf(1.f + __expf(-x));
}
// branchless tanh: tanh(x) = 1 - 2/(exp(2x)+1), exact identity, valid all x
__device__ __forceinline__ float fast_tanh(float x) {
    const float e = __expf(2.f * x);
    return 1.f - 2.f * __builtin_amdgcn_rcpf(e + 1.f);
}
__device__ __forceinline__ half8 cvt8(const float* p) {
    const float4 a = *(const float4*)p;
    const float4 b = *(const float4*)(p + 4);
    half8 t;
    t[0] = (_Float16)a.x; t[1] = (_Float16)a.y;
    t[2] = (_Float16)a.z; t[3] = (_Float16)a.w;
    t[4] = (_Float16)b.x; t[5] = (_Float16)b.y;
    t[6] = (_Float16)b.z; t[7] = (_Float16)b.w;
    return t;
}
// agent-scope cache-bypassing 16B read (R12-proven; no buffer_inv needed)
__device__ __forceinline__ half8 ld_agent16(const _Float16* p) {
    unsigned long long lo = __hip_atomic_load(
        (const unsigned long long*)p, __ATOMIC_RELAXED, __HIP_MEMORY_SCOPE_AGENT);
    unsigned long long hi = __hip_atomic_load(
        (const unsigned long long*)(p + 4), __ATOMIC_RELAXED, __HIP_MEMORY_SCOPE_AGENT);
    const h4 l4 = __builtin_bit_cast(h4, lo);
    const h4 h4_ = __builtin_bit_cast(h4, hi);
    half8 t;
    t[0] = l4[0]; t[1] = l4[1]; t[2] = l4[2]; t[3] = l4[3];
    t[4] = h4_[0]; t[5] = h4_[1]; t[6] = h4_[2]; t[7] = h4_[3];
    return t;
}
// R13: LDS-only barrier — orders hbuf writes vs next-step reads WITHOUT
// draining vmcnt (the per-step __syncthreads forced every p-prefetch load
// and h-store to complete inside its issuing step; this lets them span
// steps; compiler still inserts vmcnt(N) waits before register USE).
// sched_barrier(0) fences per guide rule #18 (no hoisting across asm waits).
__device__ __forceinline__ void lds_barrier() {
    __builtin_amdgcn_sched_barrier(0);
    asm volatile("s_waitcnt lgkmcnt(0)" ::: "memory");
    __builtin_amdgcn_s_barrier();
    __builtin_amdgcn_sched_barrier(0);
}

// ---------------------------------------------------------------------------
// cvt_rows: f32 [nrows][sk] -> f16 [nrows][dk], zero-padding cols sk..dk-1.
// ---------------------------------------------------------------------------
__global__ __launch_bounds__(256) void cvt_rows(
    const float* __restrict__ src, _Float16* __restrict__ dst,
    int nrows, int sk, int dk)
{
    const int lane   = threadIdx.x & 63;
    const int wid    = (blockIdx.x * 256 + threadIdx.x) >> 6;
    const int nw     = (gridDim.x * 256) >> 6;
    for (int row = wid; row < nrows; row += nw) {
        for (int c0 = 0; c0 < dk; c0 += 256) {
            const int c = c0 + lane * 4;
            if (c >= dk) continue;
            if (c + 4 <= sk) {
                const float4 u = *(const float4*)(src + (size_t)row * sk + c);
                h4 t; t[0] = (_Float16)u.x; t[1] = (_Float16)u.y;
                      t[2] = (_Float16)u.z; t[3] = (_Float16)u.w;
                *(h4*)(dst + (size_t)row * dk + c) = t;
            } else {
#pragma unroll
                for (int jj = 0; jj < 4; ++jj) {
                    const int cc = c + jj;
                    if (cc < dk)
                        dst[(size_t)row * dk + cc] =
                            (cc < sk) ? (_Float16)src[(size_t)row * sk + cc]
                                      : (_Float16)0.f;
                }
            }
        }
    }
}

// ---------------------------------------------------------------------------
// gemm_f16 (proven R9): C = act(A @ W^T + b1 (+b2)); A,W f16, C f32.
// ---------------------------------------------------------------------------
#define BM 128
#define BN 64
#define BK 64
#define LDK 88

template<int ACT>
__global__ __launch_bounds__(256) void gemm_f16(
    const _Float16* __restrict__ A, const _Float16* __restrict__ W,
    const float* __restrict__ b1, const float* __restrict__ b2,
    float* __restrict__ C, int M, int Ka, int Ncols)
{
    __shared__ _Float16 As[BM][LDK];
    __shared__ _Float16 Ws[BN][LDK];

    const int tid  = threadIdx.x;
    const int wave = tid >> 6;
    const int lane = tid & 63;
    const int r    = lane & 15;
    const int q    = lane >> 4;
    const int m0   = blockIdx.y * BM;
    const int n0   = blockIdx.x * BN;
    const int wm   = (wave >> 1) * 64;
    const int wn   = (wave & 1) * 32;

    const int r32 = tid >> 3;        // staging row sub-index 0..31
    const int c8  = (tid & 7) * 8;   // staging k-offset (f16 elems)

    f32x4 acc[4][2];
#pragma unroll
    for (int i = 0; i < 4; ++i)
#pragma unroll
        for (int j = 0; j < 2; ++j) acc[i][j] = f32x4{0.f, 0.f, 0.f, 0.f};

    for (int kc = 0; kc < Ka; kc += BK) {
#pragma unroll
        for (int it = 0; it < 4; ++it) {
            const int row = it * 32 + r32;
            *(half8*)&As[row][c8] =
                *(const half8*)(A + (size_t)(m0 + row) * Ka + kc + c8);
        }
#pragma unroll
        for (int it = 0; it < 2; ++it) {
            const int row  = it * 32 + r32;
            const int wrow = n0 + row;
            half8 t = {};
            if (wrow < Ncols)
                t = *(const half8*)(W + (size_t)wrow * Ka + kc + c8);
            *(half8*)&Ws[row][c8] = t;
        }
        __syncthreads();

#pragma unroll
        for (int s = 0; s < 2; ++s) {
            const int kb = s * 32 + q * 8;
            half8 af[4], wfr[2];
#pragma unroll
            for (int i = 0; i < 4; ++i)
                af[i] = *(const half8*)&As[wm + i * 16 + r][kb];
#pragma unroll
            for (int j = 0; j < 2; ++j)
                wfr[j] = *(const half8*)&Ws[wn + j * 16 + r][kb];
#pragma unroll
            for (int i = 0; i < 4; ++i)
#pragma unroll
                for (int j = 0; j < 2; ++j)
                    acc[i][j] = __builtin_amdgcn_mfma_f32_16x16x32_f16(
                        af[i], wfr[j], acc[i][j], 0, 0, 0);
        }
        __syncthreads();
    }

#pragma unroll
    for (int i = 0; i < 4; ++i) {
#pragma unroll
        for (int j = 0; j < 2; ++j) {
            const int col = n0 + wn + j * 16 + r;
            if (col < Ncols) {
                const float bias = b1[col] + (b2 ? b2[col] : 0.f);
#pragma unroll
                for (int reg = 0; reg < 4; ++reg) {
                    const int row = m0 + wm + i * 16 + q * 4 + reg;
                    float v = acc[i][j][reg] + bias;
                    if (ACT == 1) v = fast_sigmoid(v);
                    C[(size_t)row * Ncols + col] = v;
                }
            }
        }
    }
}

// ---------------------------------------------------------------------------
// lstm_mega R13: R12-verbatim pipeline with the per-step barrier changed
// from __syncthreads (vmcnt(0)+lgkmcnt(0) drain) to an LDS-only barrier
// (lgkmcnt(0)+s_barrier). The per-step vmcnt drain was the last untouched
// structural difference vs the 1332-cyc standalone step (R10/R12 falsified
// fence count, poll invs, acquire invs): it forced p-prefetch loads to
// complete within their issuing step and stores to ack before each barrier.
// Now loads get a >=2-step shadow; stores float until the chunk tail.
// Chunk-tail publish keeps the FULL proven recipe: __syncthreads (vmcnt
// drain, all waves) -> tid0 __threadfence (wbl2) -> relaxed flag store.
// Publish cadence reverted to per-chunk (R10 proved cadence is cost-free;
// this trims L2's trailing lag ~40 steps). h1g reads stay R12's relaxed
// agent-scope loads (no acquire anywhere).
// ---------------------------------------------------------------------------
__global__ __launch_bounds__(256, 1) void lstm_mega(
    const float* __restrict__ pre1, const float* __restrict__ states_in,
    const float* __restrict__ Whh1, const float* __restrict__ Whh2,
    const float* __restrict__ Wih2, const float* __restrict__ bih2,
    const float* __restrict__ bhh2,
    _Float16* __restrict__ h1g,        // [M][128] f16 handoff (mask region)
    _Float16* __restrict__ h2seq,      // [M][128] f16 (bufB) for K5
    float* __restrict__ states_out, int* __restrict__ flags)
{
    const int layer = blockIdx.x >> 6;
    const int n     = blockIdx.x & 63;
    const int tid   = threadIdx.x;
    const int w     = tid >> 6;
    const int lane  = tid & 63;
    const int r     = lane & 15;
    const int q     = lane >> 4;
    const int b     = q & 1;
    const int j     = 32 * w + 16 * b + r;   // this lane's output index
    const int h_row0 = layer ? 128 : 0;

    __shared__ __align__(16) _Float16 hbuf[2][HID];
    __shared__ __align__(16) float pre2ck[CH][GATES + 4];

    // ---- recurrence weights: wf[g][b2][s], row = 128g + 32w + 16b2 + r
    const float* Whh = layer ? Whh2 : Whh1;
    half8 wf[4][2][4];
#pragma unroll
    for (int g = 0; g < 4; ++g)
#pragma unroll
        for (int b2 = 0; b2 < 2; ++b2) {
            const float* src = Whh + (size_t)(128 * g + 32 * w + 16 * b2 + r) * HID + q * 8;
#pragma unroll
            for (int s = 0; s < 4; ++s) wf[g][b2][s] = cvt8(src + s * 32);
        }

    // ---- layer-2 extra: Wih2 B-frags (wave w owns pre2 cols 128w..128w+127)
    half8 wih[8][4];
    float bias2v[8];
    if (layer == 1) {
#pragma unroll
        for (int fi = 0; fi < 8; ++fi) {
            const int row = 128 * w + 16 * fi + r;
            const float* src = Wih2 + (size_t)row * HID + q * 8;
#pragma unroll
            for (int s = 0; s < 4; ++s) wih[fi][s] = cvt8(src + s * 32);
            bias2v[fi] = bih2[row] + bhh2[row];
        }
    }

    float c_r = states_in[(size_t)(h_row0 + 64 + n) * HID + j];
    if (tid < HID)
        hbuf[0][tid] = (_Float16)states_in[(size_t)(h_row0 + n) * HID + tid];
    __syncthreads();

    // layer-1: pre1 prefetch registers
    const float* pre_n = pre1 + (size_t)n * TSEQ * GATES;
    float pc0 = 0.f, pc1 = 0.f, pc2 = 0.f, pc3 = 0.f;
    float pn0 = 0.f, pn1 = 0.f, pn2 = 0.f, pn3 = 0.f;
    if (layer == 0) {
        pc0 = pre_n[j];           pc1 = pre_n[j + 128];
        pc2 = pre_n[j + 256];     pc3 = pre_n[j + 384];
        pn0 = pre_n[GATES + j];       pn1 = pre_n[GATES + j + 128];
        pn2 = pre_n[GATES + j + 256]; pn3 = pre_n[GATES + j + 384];
    }

    const f32x4 Z = {0.f, 0.f, 0.f, 0.f};
    int cur = 0, ts = 0, ck = 0;   // step-within-chunk, chunk index

    for (int t = 0; t < TSEQ; ++t) {
        // ==== layer-2 chunk head: wait for h1 chunk ck, compute pre2ck ====
        if (layer == 1 && ts == 0) {
            if (tid == 0) {                   // relaxed spin (R10-validated)
                while (__hip_atomic_load(flags + n, __ATOMIC_RELAXED,
                                         __HIP_MEMORY_SCOPE_AGENT) < ck + 1)
                    __builtin_amdgcn_s_sleep(2);
            }
            __syncthreads();
            // no acquire: h1g read via cache-bypassing agent loads (R12)

            const _Float16* hbase = h1g + ((size_t)n * TSEQ + (size_t)ck * CH) * HID;
#pragma unroll
            for (int mt = 0; mt < 3; ++mt) {
                const int mrow = (mt < 2) ? (mt * 16 + r) : (32 + (r & 7));
                const _Float16* src = hbase + (size_t)mrow * HID + q * 8;
                half8 ax[4];
#pragma unroll
                for (int s = 0; s < 4; ++s)
                    ax[s] = ld_agent16(src + s * 32);
                f32x4 gacc[8];
#pragma unroll
                for (int fi = 0; fi < 8; ++fi)
                    gacc[fi] = __builtin_amdgcn_mfma_f32_16x16x32_f16(
                        ax[0], wih[fi][0], Z, 0, 0, 0);
#pragma unroll
                for (int s = 1; s < 4; ++s)
#pragma unroll
                    for (int fi = 0; fi < 8; ++fi)
                        gacc[fi] = __builtin_amdgcn_mfma_f32_16x16x32_f16(
                            ax[s], wih[fi][s], gacc[fi], 0, 0, 0);
                if (mt < 2 || q < 2) {
#pragma unroll
                    for (int fi = 0; fi < 8; ++fi)
#pragma unroll
                        for (int reg = 0; reg < 4; ++reg)
                            pre2ck[mt * 16 + 4 * q + reg][128 * w + 16 * fi + r] =
                                gacc[fi][reg] + bias2v[fi];
                }
            }
            __syncthreads();
        }

        // ==== gate pre-activations ====
        float p0, p1, p2, p3;
        if (layer == 0) {
            p0 = pc0; p1 = pc1; p2 = pc2; p3 = pc3;
            pc0 = pn0; pc1 = pn1; pc2 = pn2; pc3 = pn3;
            if (t + 2 < TSEQ) {
                const float* pp = pre_n + (size_t)(t + 2) * GATES + j;
                pn0 = pp[0]; pn1 = pp[128]; pn2 = pp[256]; pn3 = pp[384];
            }
        } else {
            p0 = pre2ck[ts][j];
            p1 = pre2ck[ts][j + 128];
            p2 = pre2ck[ts][j + 256];
            p3 = pre2ck[ts][j + 384];
        }

        // ==== recurrent matvec (MFMA) ====
        half8 hx[4];
#pragma unroll
        for (int s = 0; s < 4; ++s)
            hx[s] = *(const half8*)&hbuf[cur][s * 32 + q * 8];

        f32x4 acc[4][2];
#pragma unroll
        for (int g = 0; g < 4; ++g)
#pragma unroll
            for (int b2 = 0; b2 < 2; ++b2)
                acc[g][b2] = __builtin_amdgcn_mfma_f32_16x16x32_f16(
                    hx[0], wf[g][b2][0], Z, 0, 0, 0);
#pragma unroll
        for (int s = 1; s < 4; ++s)
#pragma unroll
            for (int g = 0; g < 4; ++g)
#pragma unroll
                for (int b2 = 0; b2 < 2; ++b2)
                    acc[g][b2] = __builtin_amdgcn_mfma_f32_16x16x32_f16(
                        hx[s], wf[g][b2][s], acc[g][b2], 0, 0, 0);

        const float A0 = (b ? acc[0][1][0] : acc[0][0][0]) + p0;
        const float A1 = (b ? acc[1][1][0] : acc[1][0][0]) + p1;
        const float A2 = (b ? acc[2][1][0] : acc[2][0][0]) + p2;
        const float A3 = (b ? acc[3][1][0] : acc[3][0][0]) + p3;

        const float gi = fast_sigmoid(A0);
        const float gf = fast_sigmoid(A1);
        const float gg = fast_tanh(A2);
        const float go = fast_sigmoid(A3);

        const float cn = gf * c_r + gi * gg;
        const float hh = go * fast_tanh(cn);
        c_r = cn;

        // ==== state writes ====
        if (q < 2) {
            hbuf[cur ^ 1][j] = (_Float16)hh;
            if (t == TSEQ - 1)
                states_out[(size_t)(h_row0 + 64 + n) * HID + j] = cn;
        } else {
            if (layer == 0)
                h1g[((size_t)n * TSEQ + t) * HID + j] = (_Float16)hh;
            else
                h2seq[((size_t)n * TSEQ + t) * HID + j] = (_Float16)hh;
            if (t == TSEQ - 1)
                states_out[(size_t)(h_row0 + n) * HID + j] = hh;
        }

        // per-step: LDS-only barrier (no vmcnt drain)
        lds_barrier();

        // ==== layer-1 chunk tail: full drain + publish (proven recipe) ====
        if (layer == 0 && ts == CH - 1) {
            __syncthreads();   // drains vmcnt(0) per wave: h1g chunk complete
            if (tid == 0) {
                __threadfence();   // agent release (wbl2)
                __hip_atomic_store(flags + n, ck + 1,
                                   __ATOMIC_RELAXED, __HIP_MEMORY_SCOPE_AGENT);
            }
        }

        if (++ts == CH) { ts = 0; ++ck; }
        cur ^= 1;
    }
}

// ---------------------------------------------------------------------------
extern "C" void kernel_launch(void* const* d_in, const int* in_sizes, int n_in,
                              void* d_out, int out_size, void* d_ws, size_t ws_size,
                              hipStream_t stream)
{
    const float* x     = (const float*)d_in[0];
    const float* st_in = (const float*)d_in[1];
    const float* Wih1  = (const float*)d_in[2];
    const float* Whh1  = (const float*)d_in[3];
    const float* bih1  = (const float*)d_in[4];
    const float* bhh1  = (const float*)d_in[5];
    const float* Wih2  = (const float*)d_in[6];
    const float* Whh2  = (const float*)d_in[7];
    const float* bih2  = (const float*)d_in[8];
    const float* bhh2  = (const float*)d_in[9];
    const float* Wd    = (const float*)d_in[10];
    const float* bd    = (const float*)d_in[11];

    float* out_mask   = (float*)d_out;
    float* out_states = (float*)d_out + (size_t)NBATCH * TSEQ * DIN;

    const int M = NBATCH * TSEQ;
    float* bufA = (float*)d_ws;               // [M,512] f32 pre1
    float* bufB = bufA + (size_t)M * GATES;   // h2seq f16 + converted weights

    // bufB carve-up: h2seq f16 [M][128] (16.4MB), then Wih1h, then Wdh.
    _Float16* h2seq = (_Float16*)bufB;
    _Float16* wih1h = h2seq + (size_t)M * HID;            // [512][320]
    _Float16* wdh   = wih1h + (size_t)GATES * KP1;        // [257][128]

    // mask-region carve-up (overwritten by K5 strictly afterwards):
    //   xh f16 [M][320] (41MB), h1g f16 [M][128] (16.4MB), flags at tail.
    _Float16* xh  = (_Float16*)out_mask;
    _Float16* h1g = xh + (size_t)M * KP1;
    int* flags = (int*)(out_mask + (size_t)NBATCH * TSEQ * DIN) - 64;
    hipMemsetAsync(flags, 0, 64 * sizeof(int), stream);

    // K0: f32 -> f16 conversions (memory-bound, ~18us total)
    cvt_rows<<<256, 256, 0, stream>>>(x,    xh,    M,     DIN, KP1);
    cvt_rows<<<8,   256, 0, stream>>>(Wih1, wih1h, GATES, DIN, KP1);
    cvt_rows<<<8,   256, 0, stream>>>(Wd,   wdh,   DIN,   HID, HID);

    // K1: pre1 = xh @ Wih1h^T + bih1 + bhh1   (f16 in, M=64000, Ka=320)
    gemm_f16<0><<<dim3(GATES / BN, M / BM), 256, 0, stream>>>(
        xh, wih1h, bih1, bhh1, bufA, M, KP1, GATES);

    // K2: fused pipelined L1 rec -> h1 handoff -> (pre2 on reader) -> L2 rec
    lstm_mega<<<128, 256, 0, stream>>>(
        bufA, st_in, Whh1, Whh2, Wih2, bih2, bhh2, h1g, h2seq, out_states, flags);

    // K5: mask = sigmoid(h2seq @ Wdh^T + bd)   (f16 in, Ka=128, N=257)
    gemm_f16<1><<<dim3((DIN + BN - 1) / BN, M / BM), 256, 0, stream>>>(
        h2seq, wdh, bd, nullptr, out_mask, M, HID, DIN);
}